// Round 4
// baseline (326.948 us; speedup 1.0000x reference)
//
#include <hip/hip_runtime.h>
#include <stdint.h>

// x(4096x2048) @ W(2048x2048) + bias + probs, tanh.
static constexpr int MM = 4096;  // rows of x / out
static constexpr int KK = 2048;  // inner dim
static constexpr int NN = 2048;  // cols of out

typedef float floatx16 __attribute__((ext_vector_type(16)));
typedef __bf16 bf16x8 __attribute__((ext_vector_type(8)));
typedef unsigned short u16x8 __attribute__((ext_vector_type(8)));

__device__ __forceinline__ unsigned short bf16_rne(float x) {
  union { float f; uint32_t u; } c; c.f = x;
  uint32_t u = c.u;
  u += 0x7fffu + ((u >> 16) & 1u);
  return (unsigned short)(u >> 16);
}
__device__ __forceinline__ float bf16_as_f32(unsigned short h) {
  union { float f; uint32_t u; } c; c.u = ((uint32_t)h) << 16;
  return c.f;
}
__device__ __forceinline__ float fast_tanh(float x) {
  float e = __expf(2.0f * x);
  return 1.0f - 2.0f / (e + 1.0f);
}

// Swizzled-packed layout (row-major, 2048 k per row): within each 64-k group
// the eight 16B chunks are permuted per row: phys = (c8 + row) & 7.
// Fragment ds_read_b128 phases then hit all 32 banks at 2 lanes/bank ->
// conflict-free (verified: SQ_LDS_BANK_CONFLICT 8.4M -> 0 in R2/R3).

// ---- Pre-pass 1: split x (f32, MMxKK) -> swizzle-packed hi/lo bf16 --------
__global__ __launch_bounds__(256) void split_x_kernel(
    const float* __restrict__ in, unsigned short* __restrict__ hi,
    unsigned short* __restrict__ lo, int nchunks) {
  int idx = blockIdx.x * 256 + threadIdx.x;  // one 8-elem chunk per thread
  if (idx >= nchunks) return;
  int row = idx >> 8;        // KK/8 = 256 chunks per row
  int ck = idx & 255;        // logical chunk in row
  int g = ck >> 3;           // 64-k group
  int c8 = ck & 7;           // logical chunk within group
  const float4* s = (const float4*)(in + (size_t)row * KK + ck * 8);
  float4 v0 = s[0], v1 = s[1];
  float vv[8] = {v0.x, v0.y, v0.z, v0.w, v1.x, v1.y, v1.z, v1.w};
  u16x8 h, l;
#pragma unroll
  for (int e = 0; e < 8; e++) {
    unsigned short hh = bf16_rne(vv[e]);
    h[e] = hh;
    l[e] = bf16_rne(vv[e] - bf16_as_f32(hh));
  }
  size_t dst = (size_t)row * KK + g * 64 + ((c8 + row) & 7) * 8;
  *(u16x8*)(hi + dst) = h;
  *(u16x8*)(lo + dst) = l;
}

// ---- Pre-pass 2: W (KKxNN f32) -> Bt hi/lo swizzle-packed (NNxKK bf16) ----
__global__ __launch_bounds__(256) void wsplit_kernel(
    const float* __restrict__ W, unsigned short* __restrict__ bhi,
    unsigned short* __restrict__ blo) {
  __shared__ float tile[64][65];
  const int tid = threadIdx.x;
  const int n0 = blockIdx.x * 64;
  const int k0 = blockIdx.y * 64;   // multiple of 64 -> one swizzle group
#pragma unroll
  for (int i = 0; i < 4; i++) {
    int t = tid + i * 256;       // 0..1023
    int kr = t >> 4;             // 0..63
    int nc = (t & 15) * 4;       // 0..60
    const float4 v = *(const float4*)(W + (size_t)(k0 + kr) * NN + n0 + nc);
    tile[nc + 0][kr] = v.x;
    tile[nc + 1][kr] = v.y;
    tile[nc + 2][kr] = v.z;
    tile[nc + 3][kr] = v.w;
  }
  __syncthreads();
  const int nl = tid >> 2;       // 0..63 local n
  const int q = tid & 3;         // 2 chunks each
  const int n = n0 + nl;
#pragma unroll
  for (int cc = 0; cc < 2; cc++) {
    int c8 = q * 2 + cc;         // logical chunk 0..7 within the 64-k group
    u16x8 h, l;
#pragma unroll
    for (int e = 0; e < 8; e++) {
      float v = tile[nl][c8 * 8 + e];
      unsigned short hh = bf16_rne(v);
      h[e] = hh;
      l[e] = bf16_rne(v - bf16_as_f32(hh));
    }
    size_t dst = (size_t)n * KK + k0 + ((c8 + n) & 7) * 8;
    *(u16x8*)(bhi + dst) = h;
    *(u16x8*)(blo + dst) = l;
  }
}

// ---- Pre-pass 3: probs collapse (gate is translation-inv on uniform state)
__global__ __launch_bounds__(64) void bias_probs_kernel(
    const float* __restrict__ E, const float* __restrict__ cb,
    float* __restrict__ bias2) {
  int i = blockIdx.x * 64 + threadIdx.x;
  if (i >= NN) return;
  float p = 1.0f / 2048.0f;
#pragma unroll
  for (int d = 0; d < 9; d++) {
    const float4 a = *(const float4*)(E + (size_t)d * (2048 * 2048) + (size_t)i * 2048);
    float c0 = cosf(a.x), c1 = cosf(a.y), c2 = cosf(a.z);
    p *= (c0 * c0) * (c1 * c1) * (c2 * c2);
  }
  bias2[i] = cb[i] + p;
}

// ---- Main GEMM: 3-term bf16 split, 128x128 tile, BK=64, 32x32x16 MFMA -----
// grid 512 blocks = 2 blocks/CU grid-limited, so 64KB LDS costs nothing.
#define GLL(dst, src)                                                        \
  __builtin_amdgcn_global_load_lds(                                          \
      (const __attribute__((address_space(1))) void*)(src),                  \
      (__attribute__((address_space(3))) void*)(dst), 16, 0, 0)

__global__ __launch_bounds__(256, 2) void gemm_tanh_kernel(
    const unsigned short* __restrict__ Ahi, const unsigned short* __restrict__ Alo,
    const unsigned short* __restrict__ Bhi, const unsigned short* __restrict__ Blo,
    const float* __restrict__ bias2, float* __restrict__ out) {
  __shared__ __align__(16) unsigned short sA[2][128 * 64];  // 32 KB (hi/lo)
  __shared__ __align__(16) unsigned short sB[2][128 * 64];  // 32 KB (hi/lo)

  const int tid = threadIdx.x;
  const int lane = tid & 63;
  const int wave = tid >> 6;
  const int wm = (wave >> 1) * 64;   // wave: 64m x 64n as 2x2 of 32x32
  const int wn = (wave & 1) * 64;
  const int bm = blockIdx.y * 128;
  const int bn = blockIdx.x * 128;

  // staging: pass p covers rows 32p..32p+31; thread t -> row t>>3, chunk t&7
  const int srow = tid >> 3;
  const size_t a_base = (size_t)(bm + srow) * KK + (tid & 7) * 8;
  const size_t b_base = (size_t)(bn + srow) * KK + (tid & 7) * 8;
  const int lds_off = tid * 8;  // lane*16B contiguous per wave (GLL constraint)

  const int r31 = lane & 31;    // fragment row within 32x32 tile
  const int half = lane >> 5;   // k-half within 16-k step

  floatx16 acc[2][2];
#pragma unroll
  for (int i = 0; i < 2; i++)
#pragma unroll
    for (int j = 0; j < 2; j++)
#pragma unroll
      for (int r = 0; r < 16; r++) acc[i][j][r] = 0.f;

  for (int k0 = 0; k0 < KK; k0 += 64) {
#pragma unroll
    for (int p = 0; p < 4; p++) {
      const size_t go = k0 + (size_t)(32 * p) * KK;
      const int lo = p * 2048 + lds_off;
      GLL(&sA[0][lo], Ahi + a_base + go);
      GLL(&sA[1][lo], Alo + a_base + go);
      GLL(&sB[0][lo], Bhi + b_base + go);
      GLL(&sB[1][lo], Blo + b_base + go);
    }
    __syncthreads();

#pragma unroll
    for (int s = 0; s < 4; s++) {   // 16-k steps
      const int c8 = s * 2 + half;  // logical 16B chunk 0..7
      bf16x8 fa[2][2], fb[2][2];    // [plane][tile]
#pragma unroll
      for (int t = 0; t < 2; t++) {
        int rowA = wm + t * 32 + r31;
        int ao = rowA * 64 + ((c8 + rowA) & 7) * 8;  // de-swizzle
        fa[0][t] = *(const bf16x8*)(&sA[0][ao]);
        fa[1][t] = *(const bf16x8*)(&sA[1][ao]);
        int rowB = wn + t * 32 + r31;
        int bo = rowB * 64 + ((c8 + rowB) & 7) * 8;
        fb[0][t] = *(const bf16x8*)(&sB[0][bo]);
        fb[1][t] = *(const bf16x8*)(&sB[1][bo]);
      }
#pragma unroll
      for (int i = 0; i < 2; i++)
#pragma unroll
        for (int j = 0; j < 2; j++) {
          acc[i][j] = __builtin_amdgcn_mfma_f32_32x32x16_bf16(fa[0][i], fb[0][j], acc[i][j], 0, 0, 0);
          acc[i][j] = __builtin_amdgcn_mfma_f32_32x32x16_bf16(fa[0][i], fb[1][j], acc[i][j], 0, 0, 0);
          acc[i][j] = __builtin_amdgcn_mfma_f32_32x32x16_bf16(fa[1][i], fb[0][j], acc[i][j], 0, 0, 0);
        }
    }
    __syncthreads();
  }

  // 32x32 C/D layout: col=lane&31, row=(reg&3)+8*(reg>>2)+4*(lane>>5)
  // [m74/m101-verified]
#pragma unroll
  for (int j = 0; j < 2; j++) {
    int col = bn + wn + j * 32 + r31;
    float b2 = bias2[col];
#pragma unroll
    for (int i = 0; i < 2; i++) {
      int row0 = bm + wm + i * 32 + 4 * half;
#pragma unroll
      for (int r = 0; r < 16; r++) {
        int row = row0 + (r & 3) + 8 * (r >> 2);
        out[(size_t)row * NN + col] = fast_tanh(acc[i][j][r] + b2);
      }
    }
  }
}

// ---- Fallback (ws too small): naive fp32 ---------------------------------
__global__ __launch_bounds__(256) void fallback_gemm(
    const float* __restrict__ x, const float* __restrict__ E,
    const float* __restrict__ W, const float* __restrict__ cb,
    float* __restrict__ out) {
  __shared__ float sA[16][16];
  __shared__ float sB[16][17];
  __shared__ float sbias[16];
  const int tx = threadIdx.x, ty = threadIdx.y;
  const int row = blockIdx.y * 16 + ty;
  const int col = blockIdx.x * 16 + tx;
  if (ty == 0) {
    float p = 1.0f / 2048.0f;
    for (int d = 0; d < 9; d++) {
      const float* a = E + (size_t)d * (2048 * 2048) + (size_t)col * 2048;
      for (int t = 0; t < 3; t++) { float c = cosf(a[t]); p *= c * c; }
    }
    sbias[tx] = p + cb[col];
  }
  float acc = 0.f;
  for (int k0 = 0; k0 < KK; k0 += 16) {
    __syncthreads();
    sA[ty][tx] = x[(size_t)row * KK + k0 + tx];
    sB[ty][tx] = W[(size_t)(k0 + ty) * NN + col];
    __syncthreads();
#pragma unroll
    for (int kk = 0; kk < 16; kk++) acc += sA[ty][kk] * sB[kk][tx];
  }
  out[(size_t)row * NN + col] = tanhf(acc + sbias[tx]);
}

extern "C" void kernel_launch(void* const* d_in, const int* in_sizes, int n_in,
                              void* d_out, int out_size, void* d_ws, size_t ws_size,
                              hipStream_t stream) {
  const float* x  = (const float*)d_in[0];
  const float* E  = (const float*)d_in[1];  // eternal_weights (9,2048,2048)
  const float* W  = (const float*)d_in[3];  // classical_weights (2048,2048)
  const float* cb = (const float*)d_in[4];  // classical_biases (2048,)
  float* out = (float*)d_out;

  const size_t MB = 1024 * 1024;
  const size_t need = 48 * MB + NN * sizeof(float);
  if (ws_size < need) {
    fallback_gemm<<<dim3(NN / 16, MM / 16), dim3(16, 16), 0, stream>>>(x, E, W, cb, out);
    return;
  }

  char* ws = (char*)d_ws;
  unsigned short* Ahi = (unsigned short*)(ws);            // 16 MB
  unsigned short* Alo = (unsigned short*)(ws + 16 * MB);  // 16 MB
  unsigned short* Bhi = (unsigned short*)(ws + 32 * MB);  //  8 MB
  unsigned short* Blo = (unsigned short*)(ws + 40 * MB);  //  8 MB
  float* bias2 = (float*)(ws + 48 * MB);                  //  8 KB

  const int nchunks = MM * KK / 8;  // 1,048,576
  split_x_kernel<<<dim3(nchunks / 256), dim3(256), 0, stream>>>(x, Ahi, Alo, nchunks);
  wsplit_kernel<<<dim3(NN / 64, KK / 64), dim3(256), 0, stream>>>(W, Bhi, Blo);
  bias_probs_kernel<<<dim3(NN / 64), dim3(64), 0, stream>>>(E, cb, bias2);
  gemm_tanh_kernel<<<dim3(NN / 128, MM / 128), dim3(256), 0, stream>>>(
      Ahi, Alo, Bhi, Blo, bias2, out);
}

// Round 5
// 311.738 us; speedup vs baseline: 1.0488x; 1.0488x over previous
//
#include <hip/hip_runtime.h>
#include <hip/hip_fp8.h>
#include <stdint.h>

// x(4096x2048) @ W(2048x2048) + bias + probs, tanh.
static constexpr int MM = 4096;
static constexpr int KK = 2048;
static constexpr int NN = 2048;

typedef float floatx16 __attribute__((ext_vector_type(16)));
typedef __bf16 bf16x8 __attribute__((ext_vector_type(8)));
typedef unsigned short u16x8 __attribute__((ext_vector_type(8)));
typedef int intx4 __attribute__((ext_vector_type(4)));
typedef int intx8 __attribute__((ext_vector_type(8)));
typedef unsigned char u8x16 __attribute__((ext_vector_type(16)));

__device__ __forceinline__ unsigned short bf16_rne(float x) {
  union { float f; uint32_t u; } c; c.f = x;
  uint32_t u = c.u;
  u += 0x7fffu + ((u >> 16) & 1u);
  return (unsigned short)(u >> 16);
}
__device__ __forceinline__ float bf16_as_f32(unsigned short h) {
  union { float f; uint32_t u; } c; c.u = ((uint32_t)h) << 16;
  return c.f;
}
__device__ __forceinline__ unsigned char f32_to_e4m3(float x) {
  __hip_fp8_e4m3 q(x);           // OCP e4m3fn, RNE + saturate
  return (unsigned char)q.__x;
}
__device__ __forceinline__ float fast_tanh(float x) {
  float e = __expf(2.0f * x);
  return 1.0f - 2.0f / (e + 1.0f);
}

// Swizzles (conflict-free incl. stride-8 lane sets — R4 fix):
//   bf16 plane, 64-k groups of eight 16B chunks: phys8 = (c8 + row + (row>>3)) & 7
//   fp8  plane, 64-k groups of four  16B chunks: phys4 = (c4 + (row>>1) + (row>>3)) & 3

// ---- Pre-pass 1: x -> Ahi (bf16), A8 = fp8(x), Al8 = fp8((x-Ahi)*512) -----
__global__ __launch_bounds__(256) void split_x_kernel(
    const float* __restrict__ in, unsigned short* __restrict__ ahi,
    unsigned char* __restrict__ a8, unsigned char* __restrict__ al8,
    int nunits) {
  int idx = blockIdx.x * 256 + threadIdx.x;   // one 16-elem unit per thread
  if (idx >= nunits) return;
  int row = idx >> 7;        // 128 units per row
  int u = idx & 127;
  int g = u >> 2;            // 64-k group
  int c4 = u & 3;            // logical 16B-fp8 chunk within group
  const float4* s = (const float4*)(in + (size_t)row * KK + u * 16);
  float v[16];
#pragma unroll
  for (int q = 0; q < 4; q++) {
    float4 t = s[q];
    v[q * 4 + 0] = t.x; v[q * 4 + 1] = t.y; v[q * 4 + 2] = t.z; v[q * 4 + 3] = t.w;
  }
  unsigned short h[16];
  u8x16 f8, fl8;
#pragma unroll
  for (int e = 0; e < 16; e++) {
    h[e] = bf16_rne(v[e]);
    float lo = v[e] - bf16_as_f32(h[e]);
    f8[e] = f32_to_e4m3(v[e]);
    fl8[e] = f32_to_e4m3(lo * 512.0f);
  }
  size_t rb = (size_t)row * KK;
#pragma unroll
  for (int cc = 0; cc < 2; cc++) {
    int c8 = c4 * 2 + cc;
    int phys8 = (c8 + row + (row >> 3)) & 7;
    u16x8 o;
#pragma unroll
    for (int e = 0; e < 8; e++) o[e] = h[cc * 8 + e];
    *(u16x8*)(ahi + rb + g * 64 + phys8 * 8) = o;
  }
  int phys4 = (c4 + (row >> 1) + (row >> 3)) & 3;
  *(u8x16*)(a8 + rb + g * 64 + phys4 * 16) = f8;
  *(u8x16*)(al8 + rb + g * 64 + phys4 * 16) = fl8;
}

// ---- Pre-pass 2: W -> Bt hi (bf16) + B8 + Bl8, swizzle-packed (NNxKK) -----
__global__ __launch_bounds__(256) void wsplit_kernel(
    const float* __restrict__ W, unsigned short* __restrict__ bhi,
    unsigned char* __restrict__ b8, unsigned char* __restrict__ bl8) {
  __shared__ float tile[64][65];
  const int tid = threadIdx.x;
  const int n0 = blockIdx.x * 64;
  const int k0 = blockIdx.y * 64;   // 64-aligned -> one swizzle group
#pragma unroll
  for (int i = 0; i < 4; i++) {
    int t = tid + i * 256;
    int kr = t >> 4;
    int nc = (t & 15) * 4;
    const float4 v = *(const float4*)(W + (size_t)(k0 + kr) * NN + n0 + nc);
    tile[nc + 0][kr] = v.x;
    tile[nc + 1][kr] = v.y;
    tile[nc + 2][kr] = v.z;
    tile[nc + 3][kr] = v.w;
  }
  __syncthreads();
  const int nl = tid >> 2;       // 0..63 local n
  const int q = tid & 3;         // 16-k unit (= fp8 chunk c4)
  const int n = n0 + nl;
  float v[16];
  unsigned short h[16];
  u8x16 f8, fl8;
#pragma unroll
  for (int e = 0; e < 16; e++) {
    v[e] = tile[nl][q * 16 + e];
    h[e] = bf16_rne(v[e]);
    float lo = v[e] - bf16_as_f32(h[e]);
    f8[e] = f32_to_e4m3(v[e]);
    fl8[e] = f32_to_e4m3(lo * 512.0f);
  }
  size_t rb = (size_t)n * KK + k0;
#pragma unroll
  for (int cc = 0; cc < 2; cc++) {
    int c8 = q * 2 + cc;
    int phys8 = (c8 + n + (n >> 3)) & 7;
    u16x8 o;
#pragma unroll
    for (int e = 0; e < 8; e++) o[e] = h[cc * 8 + e];
    *(u16x8*)(bhi + rb + phys8 * 8) = o;
  }
  int phys4 = (q + (n >> 1) + (n >> 3)) & 3;
  *(u8x16*)(b8 + rb + phys4 * 16) = f8;
  *(u8x16*)(bl8 + rb + phys4 * 16) = fl8;
}

// ---- Pre-pass 3: probs collapse (gate is translation-inv on uniform state)
__global__ __launch_bounds__(64) void bias_probs_kernel(
    const float* __restrict__ E, const float* __restrict__ cb,
    float* __restrict__ bias2) {
  int i = blockIdx.x * 64 + threadIdx.x;
  if (i >= NN) return;
  float p = 1.0f / 2048.0f;
#pragma unroll
  for (int d = 0; d < 9; d++) {
    const float4 a = *(const float4*)(E + (size_t)d * (2048 * 2048) + (size_t)i * 2048);
    float c0 = cosf(a.x), c1 = cosf(a.y), c2 = cosf(a.z);
    p *= (c0 * c0) * (c1 * c1) * (c2 * c2);
  }
  bias2[i] = cb[i] + p;
}

// ---- Main GEMM: hi term bf16 32x32x16; corrections (al*b + a*bl)*2^-9 via
//      MX-scaled fp8 MFMA (unit scales -> 2x rate). 128x128 tile, BK=64.
#define GLL(dst, src)                                                        \
  __builtin_amdgcn_global_load_lds(                                          \
      (const __attribute__((address_space(1))) void*)(src),                  \
      (__attribute__((address_space(3))) void*)(dst), 16, 0, 0)

__global__ __launch_bounds__(256, 2) void gemm_tanh_kernel(
    const unsigned short* __restrict__ Ahi, const unsigned char* __restrict__ A8,
    const unsigned char* __restrict__ Al8,
    const unsigned short* __restrict__ Bhi, const unsigned char* __restrict__ B8,
    const unsigned char* __restrict__ Bl8,
    const float* __restrict__ bias2, float* __restrict__ out) {
  __shared__ __align__(16) unsigned short sAh[128 * 64];  // 16 KB
  __shared__ __align__(16) unsigned short sBh[128 * 64];  // 16 KB
  __shared__ __align__(16) unsigned char sA8[128 * 64];   //  8 KB
  __shared__ __align__(16) unsigned char sAl[128 * 64];
  __shared__ __align__(16) unsigned char sB8[128 * 64];
  __shared__ __align__(16) unsigned char sBl[128 * 64];

  const int tid = threadIdx.x;
  const int lane = tid & 63;
  const int wave = tid >> 6;
  const int wm = (wave >> 1) * 64;   // wave: 64m x 64n as 2x2 of 32x32
  const int wn = (wave & 1) * 64;
  const int bm = blockIdx.y * 128;
  const int bn = blockIdx.x * 128;

  // bf16 staging: pass p -> rows 32p..32p+31; thread t: row t>>3, chunk t&7
  const size_t a16 = (size_t)(bm + (tid >> 3)) * KK + (tid & 7) * 8;
  const size_t b16 = (size_t)(bn + (tid >> 3)) * KK + (tid & 7) * 8;
  // fp8 staging: pass p -> rows 64p..64p+63; thread t: row t>>2, chunk t&3
  const size_t a8b = (size_t)(bm + (tid >> 2)) * KK + (tid & 3) * 16;
  const size_t b8b = (size_t)(bn + (tid >> 2)) * KK + (tid & 3) * 16;
  const int lds16 = tid * 8;   // ushort elements (= tid*16 B)
  const int lds8 = tid * 16;   // bytes

  const int r31 = lane & 31;
  const int half = lane >> 5;

  floatx16 acch[2][2], accc[2][2];
#pragma unroll
  for (int i = 0; i < 2; i++)
#pragma unroll
    for (int j = 0; j < 2; j++)
#pragma unroll
      for (int r = 0; r < 16; r++) { acch[i][j][r] = 0.f; accc[i][j][r] = 0.f; }

  for (int k0 = 0; k0 < KK; k0 += 64) {
#pragma unroll
    for (int p = 0; p < 4; p++) {
      const size_t go = k0 + (size_t)(32 * p) * KK;
      GLL(&sAh[p * 2048 + lds16], Ahi + a16 + go);
      GLL(&sBh[p * 2048 + lds16], Bhi + b16 + go);
    }
#pragma unroll
    for (int p = 0; p < 2; p++) {
      const size_t go = k0 + (size_t)(64 * p) * KK;
      GLL(&sA8[p * 4096 + lds8], A8 + a8b + go);
      GLL(&sAl[p * 4096 + lds8], Al8 + a8b + go);
      GLL(&sB8[p * 4096 + lds8], B8 + b8b + go);
      GLL(&sBl[p * 4096 + lds8], Bl8 + b8b + go);
    }
    __syncthreads();

    // hi term: 4 x 16-k steps of 32x32x16 bf16
#pragma unroll
    for (int s = 0; s < 4; s++) {
      const int c8 = s * 2 + half;
      bf16x8 fa[2], fb[2];
#pragma unroll
      for (int t = 0; t < 2; t++) {
        int rowA = wm + t * 32 + r31;
        int ao = rowA * 64 + ((c8 + rowA + (rowA >> 3)) & 7) * 8;
        fa[t] = *(const bf16x8*)(&sAh[ao]);
        int rowB = wn + t * 32 + r31;
        int bo = rowB * 64 + ((c8 + rowB + (rowB >> 3)) & 7) * 8;
        fb[t] = *(const bf16x8*)(&sBh[bo]);
      }
#pragma unroll
      for (int i = 0; i < 2; i++)
#pragma unroll
        for (int j = 0; j < 2; j++)
          acch[i][j] = __builtin_amdgcn_mfma_f32_32x32x16_bf16(fa[i], fb[j], acch[i][j], 0, 0, 0);
    }

    // corrections: one 64-k step of 32x32x64 fp8 (e4m3, unit MX scales)
    // term1: (al*512) x b ; term2: a x (bl*512)
    {
      intx8 fal[2], fb8[2];
#pragma unroll
      for (int t = 0; t < 2; t++) {
        int rowA = wm + t * 32 + r31;
        int rowB = wn + t * 32 + r31;
#pragma unroll
        for (int cc = 0; cc < 2; cc++) {
          int c4 = half * 2 + cc;
          int pa = (c4 + (rowA >> 1) + (rowA >> 3)) & 3;
          ((intx4*)&fal[t])[cc] = *(const intx4*)(&sAl[rowA * 64 + pa * 16]);
          int pb = (c4 + (rowB >> 1) + (rowB >> 3)) & 3;
          ((intx4*)&fb8[t])[cc] = *(const intx4*)(&sB8[rowB * 64 + pb * 16]);
        }
      }
#pragma unroll
      for (int i = 0; i < 2; i++)
#pragma unroll
        for (int j = 0; j < 2; j++)
          accc[i][j] = __builtin_amdgcn_mfma_scale_f32_32x32x64_f8f6f4(
              fal[i], fb8[j], accc[i][j], 0, 0, 0, 0x7f7f7f7f, 0, 0x7f7f7f7f);

      intx8 fa8[2], fbl[2];
#pragma unroll
      for (int t = 0; t < 2; t++) {
        int rowA = wm + t * 32 + r31;
        int rowB = wn + t * 32 + r31;
#pragma unroll
        for (int cc = 0; cc < 2; cc++) {
          int c4 = half * 2 + cc;
          int pa = (c4 + (rowA >> 1) + (rowA >> 3)) & 3;
          ((intx4*)&fa8[t])[cc] = *(const intx4*)(&sA8[rowA * 64 + pa * 16]);
          int pb = (c4 + (rowB >> 1) + (rowB >> 3)) & 3;
          ((intx4*)&fbl[t])[cc] = *(const intx4*)(&sBl[rowB * 64 + pb * 16]);
        }
      }
#pragma unroll
      for (int i = 0; i < 2; i++)
#pragma unroll
        for (int j = 0; j < 2; j++)
          accc[i][j] = __builtin_amdgcn_mfma_scale_f32_32x32x64_f8f6f4(
              fa8[i], fbl[j], accc[i][j], 0, 0, 0, 0x7f7f7f7f, 0, 0x7f7f7f7f);
    }
    __syncthreads();
  }

  // 32x32 C/D layout: col=lane&31, row=(reg&3)+8*(reg>>2)+4*(lane>>5)
#pragma unroll
  for (int j = 0; j < 2; j++) {
    int col = bn + wn + j * 32 + r31;
    float b2 = bias2[col];
#pragma unroll
    for (int i = 0; i < 2; i++) {
      int row0 = bm + wm + i * 32 + 4 * half;
#pragma unroll
      for (int r = 0; r < 16; r++) {
        int row = row0 + (r & 3) + 8 * (r >> 2);
        float val = acch[i][j][r] + accc[i][j][r] * (1.0f / 512.0f) + b2;
        out[(size_t)row * NN + col] = fast_tanh(val);
      }
    }
  }
}

// ---- Fallback (ws too small): naive fp32 ---------------------------------
__global__ __launch_bounds__(256) void fallback_gemm(
    const float* __restrict__ x, const float* __restrict__ E,
    const float* __restrict__ W, const float* __restrict__ cb,
    float* __restrict__ out) {
  __shared__ float sA[16][16];
  __shared__ float sB[16][17];
  __shared__ float sbias[16];
  const int tx = threadIdx.x, ty = threadIdx.y;
  const int row = blockIdx.y * 16 + ty;
  const int col = blockIdx.x * 16 + tx;
  if (ty == 0) {
    float p = 1.0f / 2048.0f;
    for (int d = 0; d < 9; d++) {
      const float* a = E + (size_t)d * (2048 * 2048) + (size_t)col * 2048;
      for (int t = 0; t < 3; t++) { float c = cosf(a[t]); p *= c * c; }
    }
    sbias[tx] = p + cb[col];
  }
  float acc = 0.f;
  for (int k0 = 0; k0 < KK; k0 += 16) {
    __syncthreads();
    sA[ty][tx] = x[(size_t)row * KK + k0 + tx];
    sB[ty][tx] = W[(size_t)(k0 + ty) * NN + col];
    __syncthreads();
#pragma unroll
    for (int kk = 0; kk < 16; kk++) acc += sA[ty][kk] * sB[kk][tx];
  }
  out[(size_t)row * NN + col] = tanhf(acc + sbias[tx]);
}

extern "C" void kernel_launch(void* const* d_in, const int* in_sizes, int n_in,
                              void* d_out, int out_size, void* d_ws, size_t ws_size,
                              hipStream_t stream) {
  const float* x  = (const float*)d_in[0];
  const float* E  = (const float*)d_in[1];  // eternal_weights (9,2048,2048)
  const float* W  = (const float*)d_in[3];  // classical_weights (2048,2048)
  const float* cb = (const float*)d_in[4];  // classical_biases (2048,)
  float* out = (float*)d_out;

  const size_t MB = 1024 * 1024;
  const size_t need = 48 * MB + NN * sizeof(float);
  if (ws_size < need) {
    fallback_gemm<<<dim3(NN / 16, MM / 16), dim3(16, 16), 0, stream>>>(x, E, W, cb, out);
    return;
  }

  char* ws = (char*)d_ws;
  unsigned short* Ahi = (unsigned short*)(ws);            // 16 MB
  unsigned short* Bhi = (unsigned short*)(ws + 16 * MB);  //  8 MB
  unsigned char* A8   = (unsigned char*)(ws + 24 * MB);   //  8 MB
  unsigned char* Al8  = (unsigned char*)(ws + 32 * MB);   //  8 MB
  unsigned char* B8   = (unsigned char*)(ws + 40 * MB);   //  4 MB
  unsigned char* Bl8  = (unsigned char*)(ws + 44 * MB);   //  4 MB
  float* bias2 = (float*)(ws + 48 * MB);                  //  8 KB

  const int nunits = MM * KK / 16;  // 524288
  split_x_kernel<<<dim3(nunits / 256), dim3(256), 0, stream>>>(x, Ahi, A8, Al8, nunits);
  wsplit_kernel<<<dim3(NN / 64, KK / 64), dim3(256), 0, stream>>>(W, Bhi, B8, Bl8);
  bias_probs_kernel<<<dim3(NN / 64), dim3(64), 0, stream>>>(E, cb, bias2);
  gemm_tanh_kernel<<<dim3(NN / 128, MM / 128), dim3(256), 0, stream>>>(
      Ahi, A8, Al8, Bhi, B8, Bl8, bias2, out);
}

// Round 6
// 302.898 us; speedup vs baseline: 1.0794x; 1.0292x over previous
//
#include <hip/hip_runtime.h>
#include <hip/hip_fp8.h>
#include <stdint.h>

// x(4096x2048) @ W(2048x2048) + bias + probs, tanh.
static constexpr int MM = 4096;
static constexpr int KK = 2048;
static constexpr int NN = 2048;

typedef float floatx16 __attribute__((ext_vector_type(16)));
typedef __bf16 bf16x8 __attribute__((ext_vector_type(8)));
typedef unsigned short u16x8 __attribute__((ext_vector_type(8)));
typedef int intx4 __attribute__((ext_vector_type(4)));
typedef int intx8 __attribute__((ext_vector_type(8)));
typedef unsigned char u8x16 __attribute__((ext_vector_type(16)));

__device__ __forceinline__ unsigned short bf16_rne(float x) {
  union { float f; uint32_t u; } c; c.f = x;
  uint32_t u = c.u;
  u += 0x7fffu + ((u >> 16) & 1u);
  return (unsigned short)(u >> 16);
}
__device__ __forceinline__ float bf16_as_f32(unsigned short h) {
  union { float f; uint32_t u; } c; c.u = ((uint32_t)h) << 16;
  return c.f;
}
__device__ __forceinline__ unsigned char f32_to_e4m3(float x) {
  __hip_fp8_e4m3 q(x);           // OCP e4m3fn, RNE + saturate
  return (unsigned char)q.__x;
}
__device__ __forceinline__ float fast_tanh(float x) {
  float e = __expf(2.0f * x);
  return 1.0f - 2.0f / (e + 1.0f);
}

// Swizzles (conflict-free incl. stride-8 lane sets — R4 fix, verified R5):
//   bf16 plane, 64-k groups of eight 16B chunks: phys8 = (c8 + row + (row>>3)) & 7
//   fp8  plane, 64-k groups of four  16B chunks: phys4 = (c4 + (row>>1) + (row>>3)) & 3

// ---- Fused pre-pass: blocks [0,2048) split x; [2048,3072) split W;
//      [3072,3080) probs+bias. One launch instead of three.
__global__ __launch_bounds__(256) void prepass_kernel(
    const float* __restrict__ x, const float* __restrict__ E,
    const float* __restrict__ W, const float* __restrict__ cb,
    unsigned short* __restrict__ ahi, unsigned char* __restrict__ a8,
    unsigned char* __restrict__ al8,
    unsigned short* __restrict__ bhi, unsigned char* __restrict__ b8,
    unsigned char* __restrict__ bl8, float* __restrict__ bias2) {
  __shared__ float tile[64][65];
  const int blk = blockIdx.x;
  const int tid = threadIdx.x;

  if (blk < 2048) {
    // ---- split x: one 16-elem unit per thread -------------------------
    int idx = blk * 256 + tid;
    int row = idx >> 7;        // 128 units per row
    int u = idx & 127;
    int g = u >> 2;            // 64-k group
    int c4 = u & 3;            // logical 16B-fp8 chunk within group
    const float4* s = (const float4*)(x + (size_t)row * KK + u * 16);
    float v[16];
#pragma unroll
    for (int q = 0; q < 4; q++) {
      float4 t = s[q];
      v[q * 4 + 0] = t.x; v[q * 4 + 1] = t.y; v[q * 4 + 2] = t.z; v[q * 4 + 3] = t.w;
    }
    unsigned short h[16];
    u8x16 f8, fl8;
#pragma unroll
    for (int e = 0; e < 16; e++) {
      h[e] = bf16_rne(v[e]);
      float lo = v[e] - bf16_as_f32(h[e]);
      f8[e] = f32_to_e4m3(v[e]);
      fl8[e] = f32_to_e4m3(lo * 512.0f);
    }
    size_t rb = (size_t)row * KK;
#pragma unroll
    for (int cc = 0; cc < 2; cc++) {
      int c8 = c4 * 2 + cc;
      int phys8 = (c8 + row + (row >> 3)) & 7;
      u16x8 o;
#pragma unroll
      for (int e = 0; e < 8; e++) o[e] = h[cc * 8 + e];
      *(u16x8*)(ahi + rb + g * 64 + phys8 * 8) = o;
    }
    int phys4 = (c4 + (row >> 1) + (row >> 3)) & 3;
    *(u8x16*)(a8 + rb + g * 64 + phys4 * 16) = f8;
    *(u8x16*)(al8 + rb + g * 64 + phys4 * 16) = fl8;
  } else if (blk < 3072) {
    // ---- transpose+split W --------------------------------------------
    const int wb = blk - 2048;        // old (bx = wb&31, by = wb>>5)
    const int n0 = (wb & 31) * 64;
    const int k0 = (wb >> 5) * 64;    // 64-aligned -> one swizzle group
#pragma unroll
    for (int i = 0; i < 4; i++) {
      int t = tid + i * 256;
      int kr = t >> 4;
      int nc = (t & 15) * 4;
      const float4 vv = *(const float4*)(W + (size_t)(k0 + kr) * NN + n0 + nc);
      tile[nc + 0][kr] = vv.x;
      tile[nc + 1][kr] = vv.y;
      tile[nc + 2][kr] = vv.z;
      tile[nc + 3][kr] = vv.w;
    }
    __syncthreads();
    const int nl = tid >> 2;       // 0..63 local n
    const int q = tid & 3;         // 16-k unit (= fp8 chunk c4)
    const int n = n0 + nl;
    float v[16];
    unsigned short h[16];
    u8x16 f8, fl8;
#pragma unroll
    for (int e = 0; e < 16; e++) {
      v[e] = tile[nl][q * 16 + e];
      h[e] = bf16_rne(v[e]);
      float lo = v[e] - bf16_as_f32(h[e]);
      f8[e] = f32_to_e4m3(v[e]);
      fl8[e] = f32_to_e4m3(lo * 512.0f);
    }
    size_t rb = (size_t)n * KK + k0;
#pragma unroll
    for (int cc = 0; cc < 2; cc++) {
      int c8 = q * 2 + cc;
      int phys8 = (c8 + n + (n >> 3)) & 7;
      u16x8 o;
#pragma unroll
      for (int e = 0; e < 8; e++) o[e] = h[cc * 8 + e];
      *(u16x8*)(bhi + rb + phys8 * 8) = o;
    }
    int phys4 = (q + (n >> 1) + (n >> 3)) & 3;
    *(u8x16*)(b8 + rb + phys4 * 16) = f8;
    *(u8x16*)(bl8 + rb + phys4 * 16) = fl8;
  } else {
    // ---- probs collapse (gate is translation-inv on uniform state) ----
    int i = (blk - 3072) * 256 + tid;
    if (i < NN) {
      float p = 1.0f / 2048.0f;
#pragma unroll
      for (int d = 0; d < 9; d++) {
        const float4 a = *(const float4*)(E + (size_t)d * (2048 * 2048) + (size_t)i * 2048);
        float c0 = cosf(a.x), c1 = cosf(a.y), c2 = cosf(a.z);
        p *= (c0 * c0) * (c1 * c1) * (c2 * c2);
      }
      bias2[i] = cb[i] + p;
    }
  }
}

// ---- Main GEMM: hi term bf16 32x32x16; corrections (al*b + a*bl)*2^-9 via
//      MX-scaled fp8 MFMA (unit scales -> 2x rate). 128x128 tile, BK=64.
//      XCD-cluster swizzle (4x4 blocks) for L2 strip sharing; NT C-stores.
#define GLL(dst, src)                                                        \
  __builtin_amdgcn_global_load_lds(                                          \
      (const __attribute__((address_space(1))) void*)(src),                  \
      (__attribute__((address_space(3))) void*)(dst), 16, 0, 0)

__global__ __launch_bounds__(256, 2) void gemm_tanh_kernel(
    const unsigned short* __restrict__ Ahi, const unsigned char* __restrict__ A8,
    const unsigned char* __restrict__ Al8,
    const unsigned short* __restrict__ Bhi, const unsigned char* __restrict__ B8,
    const unsigned char* __restrict__ Bl8,
    const float* __restrict__ bias2, float* __restrict__ out) {
  __shared__ __align__(16) unsigned short sAh[128 * 64];  // 16 KB
  __shared__ __align__(16) unsigned short sBh[128 * 64];  // 16 KB
  __shared__ __align__(16) unsigned char sA8[128 * 64];   //  8 KB
  __shared__ __align__(16) unsigned char sAl[128 * 64];
  __shared__ __align__(16) unsigned char sB8[128 * 64];
  __shared__ __align__(16) unsigned char sBl[128 * 64];

  const int tid = threadIdx.x;
  const int lane = tid & 63;
  const int wave = tid >> 6;
  const int wm = (wave >> 1) * 64;   // wave: 64m x 64n as 2x2 of 32x32
  const int wn = (wave & 1) * 64;

  // 4x4 cluster swizzle: 16 consecutive block ids cover a 512m x 512n
  // super-tile -> shared A/B strips stay hot in the XCD L2s.
  const int id = blockIdx.x;         // 0..511
  const int cid = id >> 4, lid = id & 15;
  const int bm = ((cid >> 2) * 4 + (lid >> 2)) * 128;   // 32 m-blocks
  const int bn = ((cid & 3) * 4 + (lid & 3)) * 128;     // 16 n-blocks

  // bf16 staging: pass p -> rows 32p..32p+31; thread t: row t>>3, chunk t&7
  const size_t a16 = (size_t)(bm + (tid >> 3)) * KK + (tid & 7) * 8;
  const size_t b16 = (size_t)(bn + (tid >> 3)) * KK + (tid & 7) * 8;
  // fp8 staging: pass p -> rows 64p..64p+63; thread t: row t>>2, chunk t&3
  const size_t a8b = (size_t)(bm + (tid >> 2)) * KK + (tid & 3) * 16;
  const size_t b8b = (size_t)(bn + (tid >> 2)) * KK + (tid & 3) * 16;
  const int lds16 = tid * 8;   // ushort elements (= tid*16 B)
  const int lds8 = tid * 16;   // bytes

  const int r31 = lane & 31;
  const int half = lane >> 5;

  floatx16 acch[2][2], accc[2][2];
#pragma unroll
  for (int i = 0; i < 2; i++)
#pragma unroll
    for (int j = 0; j < 2; j++)
#pragma unroll
      for (int r = 0; r < 16; r++) { acch[i][j][r] = 0.f; accc[i][j][r] = 0.f; }

  for (int k0 = 0; k0 < KK; k0 += 64) {
#pragma unroll
    for (int p = 0; p < 4; p++) {
      const size_t go = k0 + (size_t)(32 * p) * KK;
      GLL(&sAh[p * 2048 + lds16], Ahi + a16 + go);
      GLL(&sBh[p * 2048 + lds16], Bhi + b16 + go);
    }
#pragma unroll
    for (int p = 0; p < 2; p++) {
      const size_t go = k0 + (size_t)(64 * p) * KK;
      GLL(&sA8[p * 4096 + lds8], A8 + a8b + go);
      GLL(&sAl[p * 4096 + lds8], Al8 + a8b + go);
      GLL(&sB8[p * 4096 + lds8], B8 + b8b + go);
      GLL(&sBl[p * 4096 + lds8], Bl8 + b8b + go);
    }
    __syncthreads();

    // hi term: 4 x 16-k steps of 32x32x16 bf16
#pragma unroll
    for (int s = 0; s < 4; s++) {
      const int c8 = s * 2 + half;
      bf16x8 fa[2], fb[2];
#pragma unroll
      for (int t = 0; t < 2; t++) {
        int rowA = wm + t * 32 + r31;
        int ao = rowA * 64 + ((c8 + rowA + (rowA >> 3)) & 7) * 8;
        fa[t] = *(const bf16x8*)(&sAh[ao]);
        int rowB = wn + t * 32 + r31;
        int bo = rowB * 64 + ((c8 + rowB + (rowB >> 3)) & 7) * 8;
        fb[t] = *(const bf16x8*)(&sBh[bo]);
      }
#pragma unroll
      for (int i = 0; i < 2; i++)
#pragma unroll
        for (int j = 0; j < 2; j++)
          acch[i][j] = __builtin_amdgcn_mfma_f32_32x32x16_bf16(fa[i], fb[j], acch[i][j], 0, 0, 0);
    }

    // corrections: one 64-k step of 32x32x64 fp8 (e4m3, unit MX scales)
    {
      intx8 fal[2], fb8[2];
#pragma unroll
      for (int t = 0; t < 2; t++) {
        int rowA = wm + t * 32 + r31;
        int rowB = wn + t * 32 + r31;
#pragma unroll
        for (int cc = 0; cc < 2; cc++) {
          int c4 = half * 2 + cc;
          int pa = (c4 + (rowA >> 1) + (rowA >> 3)) & 3;
          ((intx4*)&fal[t])[cc] = *(const intx4*)(&sAl[rowA * 64 + pa * 16]);
          int pb = (c4 + (rowB >> 1) + (rowB >> 3)) & 3;
          ((intx4*)&fb8[t])[cc] = *(const intx4*)(&sB8[rowB * 64 + pb * 16]);
        }
      }
#pragma unroll
      for (int i = 0; i < 2; i++)
#pragma unroll
        for (int j = 0; j < 2; j++)
          accc[i][j] = __builtin_amdgcn_mfma_scale_f32_32x32x64_f8f6f4(
              fal[i], fb8[j], accc[i][j], 0, 0, 0, 0x7f7f7f7f, 0, 0x7f7f7f7f);

      intx8 fa8[2], fbl[2];
#pragma unroll
      for (int t = 0; t < 2; t++) {
        int rowA = wm + t * 32 + r31;
        int rowB = wn + t * 32 + r31;
#pragma unroll
        for (int cc = 0; cc < 2; cc++) {
          int c4 = half * 2 + cc;
          int pa = (c4 + (rowA >> 1) + (rowA >> 3)) & 3;
          ((intx4*)&fa8[t])[cc] = *(const intx4*)(&sA8[rowA * 64 + pa * 16]);
          int pb = (c4 + (rowB >> 1) + (rowB >> 3)) & 3;
          ((intx4*)&fbl[t])[cc] = *(const intx4*)(&sBl[rowB * 64 + pb * 16]);
        }
      }
#pragma unroll
      for (int i = 0; i < 2; i++)
#pragma unroll
        for (int j = 0; j < 2; j++)
          accc[i][j] = __builtin_amdgcn_mfma_scale_f32_32x32x64_f8f6f4(
              fa8[i], fbl[j], accc[i][j], 0, 0, 0, 0x7f7f7f7f, 0, 0x7f7f7f7f);
    }
    __syncthreads();
  }

  // 32x32 C/D layout: col=lane&31, row=(reg&3)+8*(reg>>2)+4*(lane>>5)
#pragma unroll
  for (int j = 0; j < 2; j++) {
    int col = bn + wn + j * 32 + r31;
    float b2 = bias2[col];
#pragma unroll
    for (int i = 0; i < 2; i++) {
      int row0 = bm + wm + i * 32 + 4 * half;
#pragma unroll
      for (int r = 0; r < 16; r++) {
        int row = row0 + (r & 3) + 8 * (r >> 2);
        float val = acch[i][j][r] + accc[i][j][r] * (1.0f / 512.0f) + b2;
        __builtin_nontemporal_store(fast_tanh(val), &out[(size_t)row * NN + col]);
      }
    }
  }
}

// ---- Fallback (ws too small): naive fp32 ---------------------------------
__global__ __launch_bounds__(256) void fallback_gemm(
    const float* __restrict__ x, const float* __restrict__ E,
    const float* __restrict__ W, const float* __restrict__ cb,
    float* __restrict__ out) {
  __shared__ float sA[16][16];
  __shared__ float sB[16][17];
  __shared__ float sbias[16];
  const int tx = threadIdx.x, ty = threadIdx.y;
  const int row = blockIdx.y * 16 + ty;
  const int col = blockIdx.x * 16 + tx;
  if (ty == 0) {
    float p = 1.0f / 2048.0f;
    for (int d = 0; d < 9; d++) {
      const float* a = E + (size_t)d * (2048 * 2048) + (size_t)col * 2048;
      for (int t = 0; t < 3; t++) { float c = cosf(a[t]); p *= c * c; }
    }
    sbias[tx] = p + cb[col];
  }
  float acc = 0.f;
  for (int k0 = 0; k0 < KK; k0 += 16) {
    __syncthreads();
    sA[ty][tx] = x[(size_t)row * KK + k0 + tx];
    sB[ty][tx] = W[(size_t)(k0 + ty) * NN + col];
    __syncthreads();
#pragma unroll
    for (int kk = 0; kk < 16; kk++) acc += sA[ty][kk] * sB[kk][tx];
  }
  out[(size_t)row * NN + col] = tanhf(acc + sbias[tx]);
}

extern "C" void kernel_launch(void* const* d_in, const int* in_sizes, int n_in,
                              void* d_out, int out_size, void* d_ws, size_t ws_size,
                              hipStream_t stream) {
  const float* x  = (const float*)d_in[0];
  const float* E  = (const float*)d_in[1];  // eternal_weights (9,2048,2048)
  const float* W  = (const float*)d_in[3];  // classical_weights (2048,2048)
  const float* cb = (const float*)d_in[4];  // classical_biases (2048,)
  float* out = (float*)d_out;

  const size_t MB = 1024 * 1024;
  const size_t need = 48 * MB + NN * sizeof(float);
  if (ws_size < need) {
    fallback_gemm<<<dim3(NN / 16, MM / 16), dim3(16, 16), 0, stream>>>(x, E, W, cb, out);
    return;
  }

  char* ws = (char*)d_ws;
  unsigned short* Ahi = (unsigned short*)(ws);            // 16 MB
  unsigned short* Bhi = (unsigned short*)(ws + 16 * MB);  //  8 MB
  unsigned char* A8   = (unsigned char*)(ws + 24 * MB);   //  8 MB
  unsigned char* Al8  = (unsigned char*)(ws + 32 * MB);   //  8 MB
  unsigned char* B8   = (unsigned char*)(ws + 40 * MB);   //  4 MB
  unsigned char* Bl8  = (unsigned char*)(ws + 44 * MB);   //  4 MB
  float* bias2 = (float*)(ws + 48 * MB);                  //  8 KB

  prepass_kernel<<<dim3(3080), dim3(256), 0, stream>>>(
      x, E, W, cb, Ahi, A8, Al8, Bhi, B8, Bl8, bias2);
  gemm_tanh_kernel<<<dim3(512), dim3(256), 0, stream>>>(
      Ahi, A8, Al8, Bhi, B8, Bl8, bias2, out);
}